// Round 6
// baseline (510.950 us; speedup 1.0000x reference)
//
#include <hip/hip_runtime.h>
#include <stdint.h>

#define SPARSE_D 41
#define SPARSE_H 1600
#define SPARSE_W 1408
#define BN_EPS 0.001f

static constexpr int NYB = SPARSE_H / 2;          // 800
static constexpr int NBUCKET = SPARSE_D * NYB;    // 32,800 buckets
static constexpr int PCAP = 12;                   // max stored non-self pairs (lambda~0.056)
static constexpr int GRIDB = 256;                 // 1 block/CU -> co-residency guaranteed
static constexpr int BLOCKT = 256;
static constexpr int GSZ = GRIDB * BLOCKT;        // 65536 threads

// bucket = z*NYB + (y>>1); 32 uint32 words (128B): word0=count, words1..31=entries
// entry: [29]=y&1, [28:18]=x (11b), [17:0]=idx
// pair:  [22:18]=k, [17:0]=idx

// ---- software grid barrier: generation counter, device scope ----
__device__ __forceinline__ void gbar(int* __restrict__ counter, int* __restrict__ gen) {
    __syncthreads();
    if (threadIdx.x == 0) {
        __threadfence();
        int g = __hip_atomic_load(gen, __ATOMIC_RELAXED, __HIP_MEMORY_SCOPE_AGENT);
        if (__hip_atomic_fetch_add(counter, 1, __ATOMIC_ACQ_REL, __HIP_MEMORY_SCOPE_AGENT) == GRIDB - 1) {
            __hip_atomic_store(counter, 0, __ATOMIC_RELAXED, __HIP_MEMORY_SCOPE_AGENT);
            __hip_atomic_fetch_add(gen, 1, __ATOMIC_ACQ_REL, __HIP_MEMORY_SCOPE_AGENT);
        } else {
            while (__hip_atomic_load(gen, __ATOMIC_ACQUIRE, __HIP_MEMORY_SCOPE_AGENT) == g)
                __builtin_amdgcn_s_sleep(2);
        }
        __threadfence();
    }
    __syncthreads();
}

// ---- block stats: thread-local sums -> wave shuffle -> LDS -> per-block partials ----
__device__ __forceinline__ void stats_epilogue2(const float s[16], const float q[16],
                                                float* __restrict__ partials,
                                                float (*sred)[32]) {
    int lid = threadIdx.x & 63;
    int wid = threadIdx.x >> 6;
    #pragma unroll
    for (int d = 0; d < 16; ++d) {
        float v = s[d], v2 = q[d];
        #pragma unroll
        for (int off = 32; off; off >>= 1) {
            v += __shfl_xor(v, off);
            v2 += __shfl_xor(v2, off);
        }
        if (lid == 0) { sred[wid][d] = v; sred[wid][16 + d] = v2; }
    }
    __syncthreads();
    if (threadIdx.x < 32)
        partials[(size_t)blockIdx.x * 32 + threadIdx.x] =
            sred[0][threadIdx.x] + sred[1][threadIdx.x] +
            sred[2][threadIdx.x] + sred[3][threadIdx.x];
    __syncthreads();
}

// ---- every block redundantly reduces all GRIDB partials -> scale/shift in LDS ----
__device__ __forceinline__ void reduce_scsh(const float* __restrict__ partials,
                                            const float* __restrict__ gamma,
                                            const float* __restrict__ beta,
                                            float invN, float (*red)[33],
                                            float* __restrict__ scsh) {
    int ch = threadIdx.x & 31;
    int rg = threadIdx.x >> 5;    // 0..7
    float s0 = 0.f, s1 = 0.f, s2 = 0.f, s3 = 0.f;
    #pragma unroll
    for (int j = 0; j < GRIDB / 32; ++j) {       // 8 iters, 4-way ILP
        int base = rg + j * 32;
        s0 += partials[(size_t)(base     ) * 32 + ch];
        s1 += partials[(size_t)(base +  8) * 32 + ch];
        s2 += partials[(size_t)(base + 16) * 32 + ch];
        s3 += partials[(size_t)(base + 24) * 32 + ch];
    }
    red[rg][ch] = (s0 + s1) + (s2 + s3);
    __syncthreads();
    if (threadIdx.x < 32) {
        float t = 0.f;
        #pragma unroll
        for (int r = 0; r < 8; ++r) t += red[r][threadIdx.x];
        red[0][threadIdx.x] = t;
    }
    __syncthreads();
    if (threadIdx.x < 16) {
        int d = threadIdx.x;
        float mean = red[0][d] * invN;
        float var  = red[0][16 + d] * invN - mean * mean;
        float sc = gamma[d] * rsqrtf(var + BN_EPS);
        scsh[d] = sc;
        scsh[16 + d] = beta[d] - mean * sc;
    }
    __syncthreads();
}

__global__ void k_mega(const int* __restrict__ coords, const float* __restrict__ feat,
                       const float* __restrict__ w1, const float* __restrict__ gamma1,
                       const float* __restrict__ beta1, const float* __restrict__ w2,
                       const float* __restrict__ gamma2, const float* __restrict__ beta2,
                       uint32_t* __restrict__ bent, uint32_t* __restrict__ pairs,
                       int* __restrict__ pcnt, float* __restrict__ partials1,
                       float* __restrict__ partials2, float* __restrict__ h1,
                       float* __restrict__ out, int* __restrict__ bar, int N) {
    __shared__ float w1s[27 * 48];       // 5184 B
    __shared__ float w2s[27 * 256];      // 27648 B
    __shared__ float red[8][33];
    __shared__ float sred[4][32];
    __shared__ float scsh[32];

    for (int i = threadIdx.x; i < 27 * 48; i += BLOCKT) w1s[i] = w1[i];
    for (int i = threadIdx.x; i < 27 * 256; i += BLOCKT) w2s[i] = w2[i];

    int* bcounter = bar;
    int* bgen = bar + 1;
    const int gtid = blockIdx.x * BLOCKT + threadIdx.x;
    const float invN = 1.f / (float)N;

    // ---- P0: zero bucket counts ----
    for (int b = gtid; b < NBUCKET; b += GSZ) bent[(size_t)b * 32] = 0u;
    gbar(bcounter, bgen);

    // ---- P1: insert voxels into buckets ----
    for (int n = gtid; n < N; n += GSZ) {
        int4 c4 = ((const int4*)coords)[n];
        int z = c4.y, y = c4.z, x = c4.w;
        int b = z * NYB + (y >> 1);
        uint32_t e = ((uint32_t)(y & 1) << 29) | ((uint32_t)x << 18) | (uint32_t)n;
        int slot = atomicAdd((int*)&bent[(size_t)b * 32], 1) + 1;
        if (slot <= 31) bent[(size_t)b * 32 + slot] = e;
    }
    gbar(bcounter, bgen);

    // ---- P2: build pairs + conv1 (raw) + BN1 stats ----
    {
        float sum1[16], sq1[16];
        #pragma unroll
        for (int d = 0; d < 16; ++d) { sum1[d] = 0.f; sq1[d] = 0.f; }
        for (int n = gtid; n < N; n += GSZ) {
            int4 c4 = ((const int4*)coords)[n];
            int z = c4.y, y = c4.z, x = c4.w;
            float acc[16];
            {
                float f0 = feat[n * 3 + 0], f1 = feat[n * 3 + 1], f2 = feat[n * 3 + 2];
                const float* wd = &w1s[13 * 48];
                #pragma unroll
                for (int d = 0; d < 16; ++d)
                    acc[d] = fmaf(f0, wd[d], fmaf(f1, wd[16 + d], f2 * wd[32 + d]));
            }
            int cnt = 0;
            auto scan_entry = [&](uint32_t e, int slot, int m, int yb, int dzk) {
                if (slot > m) return;
                int ey = (yb << 1) + (int)(e >> 29);
                int ex = (int)((e >> 18) & 0x7FFu);
                int dy = ey - y, dx = ex - x;
                if ((unsigned)(dy + 1) > 2u || (unsigned)(dx + 1) > 2u) return;
                uint32_t idx = e & 0x3FFFFu;
                if (idx == (uint32_t)n) return;
                int k = dzk + (dy + 1) * 3 + (dx + 1);
                if (cnt < PCAP) pairs[(size_t)cnt * N + n] = ((uint32_t)k << 18) | idx;
                ++cnt;
                float g0 = feat[idx * 3 + 0], g1 = feat[idx * 3 + 1], g2 = feat[idx * 3 + 2];
                const float* wk = &w1s[k * 48];
                #pragma unroll
                for (int d = 0; d < 16; ++d)
                    acc[d] = fmaf(g0, wk[d], fmaf(g1, wk[16 + d], fmaf(g2, wk[32 + d], acc[d])));
            };
            int yb0 = (y - 1) >> 1;
            #pragma unroll
            for (int dz = -1; dz <= 1; ++dz) {
                int zz = z + dz;
                if ((unsigned)zz >= SPARSE_D) continue;
                int dzk = (dz + 1) * 9;
                #pragma unroll
                for (int t = 0; t < 2; ++t) {
                    int yb = yb0 + t;
                    if ((unsigned)yb >= NYB) continue;
                    const uint4* L = (const uint4*)&bent[((size_t)zz * NYB + yb) * 32];
                    uint4 q0 = L[0], q1 = L[1], q2 = L[2], q3 = L[3];
                    int m = min((int)q0.x, 31);
                    scan_entry(q0.y,  1, m, yb, dzk);
                    scan_entry(q0.z,  2, m, yb, dzk);
                    scan_entry(q0.w,  3, m, yb, dzk);
                    scan_entry(q1.x,  4, m, yb, dzk);
                    scan_entry(q1.y,  5, m, yb, dzk);
                    scan_entry(q1.z,  6, m, yb, dzk);
                    scan_entry(q1.w,  7, m, yb, dzk);
                    scan_entry(q2.x,  8, m, yb, dzk);
                    scan_entry(q2.y,  9, m, yb, dzk);
                    scan_entry(q2.z, 10, m, yb, dzk);
                    scan_entry(q2.w, 11, m, yb, dzk);
                    scan_entry(q3.x, 12, m, yb, dzk);
                    scan_entry(q3.y, 13, m, yb, dzk);
                    scan_entry(q3.z, 14, m, yb, dzk);
                    scan_entry(q3.w, 15, m, yb, dzk);
                    if (m > 15) {
                        uint4 q4 = L[4], q5 = L[5], q6 = L[6], q7 = L[7];
                        scan_entry(q4.x, 16, m, yb, dzk);
                        scan_entry(q4.y, 17, m, yb, dzk);
                        scan_entry(q4.z, 18, m, yb, dzk);
                        scan_entry(q4.w, 19, m, yb, dzk);
                        scan_entry(q5.x, 20, m, yb, dzk);
                        scan_entry(q5.y, 21, m, yb, dzk);
                        scan_entry(q5.z, 22, m, yb, dzk);
                        scan_entry(q5.w, 23, m, yb, dzk);
                        scan_entry(q6.x, 24, m, yb, dzk);
                        scan_entry(q6.y, 25, m, yb, dzk);
                        scan_entry(q6.z, 26, m, yb, dzk);
                        scan_entry(q6.w, 27, m, yb, dzk);
                        scan_entry(q7.x, 28, m, yb, dzk);
                        scan_entry(q7.y, 29, m, yb, dzk);
                        scan_entry(q7.z, 30, m, yb, dzk);
                        scan_entry(q7.w, 31, m, yb, dzk);
                    }
                }
            }
            pcnt[n] = min(cnt, PCAP);
            float4* o = (float4*)&h1[(size_t)n * 16];
            o[0] = make_float4(acc[0], acc[1], acc[2], acc[3]);
            o[1] = make_float4(acc[4], acc[5], acc[6], acc[7]);
            o[2] = make_float4(acc[8], acc[9], acc[10], acc[11]);
            o[3] = make_float4(acc[12], acc[13], acc[14], acc[15]);
            #pragma unroll
            for (int d = 0; d < 16; ++d) {
                sum1[d] += acc[d];
                sq1[d] = fmaf(acc[d], acc[d], sq1[d]);
            }
        }
        stats_epilogue2(sum1, sq1, partials1, sred);
    }
    gbar(bcounter, bgen);

    // ---- P3: BN1 finalize (redundant per block) + conv2 with fused BN1+ReLU loads ----
    reduce_scsh(partials1, gamma1, beta1, invN, red, scsh);
    {
        float sum2[16], sq2[16];
        #pragma unroll
        for (int d = 0; d < 16; ++d) { sum2[d] = 0.f; sq2[d] = 0.f; }
        for (int n = gtid; n < N; n += GSZ) {
            float a2[16];
            #pragma unroll
            for (int d = 0; d < 16; ++d) a2[d] = 0.f;
            // self term: load raw h1, normalize
            {
                const float4* hp = (const float4*)&h1[(size_t)n * 16];
                const float* wk = &w2s[13 * 256];
                #pragma unroll
                for (int cb = 0; cb < 4; ++cb) {
                    float4 tq = hp[cb];
                    float g0 = fmaxf(fmaf(tq.x, scsh[cb * 4 + 0], scsh[16 + cb * 4 + 0]), 0.f);
                    float g1 = fmaxf(fmaf(tq.y, scsh[cb * 4 + 1], scsh[16 + cb * 4 + 1]), 0.f);
                    float g2 = fmaxf(fmaf(tq.z, scsh[cb * 4 + 2], scsh[16 + cb * 4 + 2]), 0.f);
                    float g3 = fmaxf(fmaf(tq.w, scsh[cb * 4 + 3], scsh[16 + cb * 4 + 3]), 0.f);
                    #pragma unroll
                    for (int d = 0; d < 16; ++d) {
                        a2[d] = fmaf(g0, wk[(cb * 4 + 0) * 16 + d], a2[d]);
                        a2[d] = fmaf(g1, wk[(cb * 4 + 1) * 16 + d], a2[d]);
                        a2[d] = fmaf(g2, wk[(cb * 4 + 2) * 16 + d], a2[d]);
                        a2[d] = fmaf(g3, wk[(cb * 4 + 3) * 16 + d], a2[d]);
                    }
                }
            }
            int m = pcnt[n];
            for (int cc = 0; cc < m; ++cc) {
                uint32_t pr = pairs[(size_t)cc * N + n];
                int k = (int)(pr >> 18);
                int idx = (int)(pr & 0x3FFFFu);
                const float* wk = &w2s[k * 256];
                const float4* hp = (const float4*)&h1[(size_t)idx * 16];
                #pragma unroll
                for (int cb = 0; cb < 4; ++cb) {
                    float4 tq = hp[cb];
                    float g0 = fmaxf(fmaf(tq.x, scsh[cb * 4 + 0], scsh[16 + cb * 4 + 0]), 0.f);
                    float g1 = fmaxf(fmaf(tq.y, scsh[cb * 4 + 1], scsh[16 + cb * 4 + 1]), 0.f);
                    float g2 = fmaxf(fmaf(tq.z, scsh[cb * 4 + 2], scsh[16 + cb * 4 + 2]), 0.f);
                    float g3 = fmaxf(fmaf(tq.w, scsh[cb * 4 + 3], scsh[16 + cb * 4 + 3]), 0.f);
                    #pragma unroll
                    for (int d = 0; d < 16; ++d) {
                        a2[d] = fmaf(g0, wk[(cb * 4 + 0) * 16 + d], a2[d]);
                        a2[d] = fmaf(g1, wk[(cb * 4 + 1) * 16 + d], a2[d]);
                        a2[d] = fmaf(g2, wk[(cb * 4 + 2) * 16 + d], a2[d]);
                        a2[d] = fmaf(g3, wk[(cb * 4 + 3) * 16 + d], a2[d]);
                    }
                }
            }
            float4* o = (float4*)&out[(size_t)n * 16];
            o[0] = make_float4(a2[0], a2[1], a2[2], a2[3]);
            o[1] = make_float4(a2[4], a2[5], a2[6], a2[7]);
            o[2] = make_float4(a2[8], a2[9], a2[10], a2[11]);
            o[3] = make_float4(a2[12], a2[13], a2[14], a2[15]);
            #pragma unroll
            for (int d = 0; d < 16; ++d) {
                sum2[d] += a2[d];
                sq2[d] = fmaf(a2[d], a2[d], sq2[d]);
            }
        }
        stats_epilogue2(sum2, sq2, partials2, sred);
    }
    gbar(bcounter, bgen);

    // ---- P4: BN2 finalize (redundant) + normalize out in place ----
    reduce_scsh(partials2, gamma2, beta2, invN, red, scsh);
    {
        const int nvec = N * 4;   // float4 count
        for (int i = gtid; i < nvec; i += GSZ) {
            float4 v = ((float4*)out)[i];
            int c0 = (i & 3) * 4;
            v.x = fmaxf(fmaf(v.x, scsh[c0 + 0], scsh[16 + c0 + 0]), 0.f);
            v.y = fmaxf(fmaf(v.y, scsh[c0 + 1], scsh[16 + c0 + 1]), 0.f);
            v.z = fmaxf(fmaf(v.z, scsh[c0 + 2], scsh[16 + c0 + 2]), 0.f);
            v.w = fmaxf(fmaf(v.w, scsh[c0 + 3], scsh[16 + c0 + 3]), 0.f);
            ((float4*)out)[i] = v;
        }
    }
}

extern "C" void kernel_launch(void* const* d_in, const int* in_sizes, int n_in,
                              void* d_out, int out_size, void* d_ws, size_t ws_size,
                              hipStream_t stream) {
    const float* feat   = (const float*)d_in[0];
    const int*   coords = (const int*)d_in[1];
    const float* w1     = (const float*)d_in[2];
    const float* gamma1 = (const float*)d_in[3];
    const float* beta1  = (const float*)d_in[4];
    const float* w2     = (const float*)d_in[5];
    const float* gamma2 = (const float*)d_in[6];
    const float* beta2  = (const float*)d_in[7];
    float* out = (float*)d_out;
    const int N = in_sizes[0] / 3;

    // workspace layout (64B aligned)
    char* ws = (char*)d_ws;
    size_t off = 0;
    int* bar = (int*)(ws + off);             off += 64;
    uint32_t* bent = (uint32_t*)(ws + off);  off += (size_t)NBUCKET * 32 * 4;        // 4.2 MB
    uint32_t* pairs = (uint32_t*)(ws + off); off += (size_t)PCAP * N * 4;            // 9.6 MB
    int* pcnt = (int*)(ws + off);            off += ((size_t)N * 4 + 63) & ~(size_t)63;
    float* partials1 = (float*)(ws + off);   off += (size_t)GRIDB * 32 * 4;
    float* partials2 = (float*)(ws + off);   off += (size_t)GRIDB * 32 * 4;
    float* h1 = (float*)(ws + off);          off += (size_t)N * 16 * 4;              // 12.8 MB

    hipMemsetAsync(bar, 0, 64, stream);      // barrier counter + generation
    k_mega<<<GRIDB, BLOCKT, 0, stream>>>(coords, feat, w1, gamma1, beta1,
                                         w2, gamma2, beta2, bent, pairs, pcnt,
                                         partials1, partials2, h1, out, bar, N);
}

// Round 7
// 166.215 us; speedup vs baseline: 3.0740x; 3.0740x over previous
//
#include <hip/hip_runtime.h>
#include <stdint.h>

#define SPARSE_D 41
#define SPARSE_H 1600
#define SPARSE_W 1408
#define BN_EPS 0.001f

static constexpr int NYB = SPARSE_H / 2;          // 800
static constexpr int NBUCKET = SPARSE_D * NYB;    // 32,800
static constexpr int BCAP = 32;                   // entries per bucket
static constexpr int PCAP = 12;                   // max non-self pairs per voxel (lambda~0.056)

// entry: [29]=y&1, [28:18]=x (11b), [17:0]=idx ; pair: [22:18]=k, [17:0]=idx

// ---------------- scatter voxels into buckets ----------------
__global__ void k_insert(const int* __restrict__ coords, int* __restrict__ bcnt,
                         uint32_t* __restrict__ bent, int N) {
    int n = blockIdx.x * blockDim.x + threadIdx.x;
    if (n >= N) return;
    int4 c4 = ((const int4*)coords)[n];
    int z = c4.y, y = c4.z, x = c4.w;
    int b = z * NYB + (y >> 1);
    int slot = atomicAdd(&bcnt[b], 1);
    if (slot < BCAP)
        bent[b * BCAP + slot] = ((uint32_t)(y & 1) << 29) | ((uint32_t)x << 18) | (uint32_t)n;
}

// ---- stats epilogue: wave shuffle reduce -> LDS -> per-block partials ----
__device__ __forceinline__ void stats_epilogue(const float acc[16],
                                               float* __restrict__ partials,
                                               float (*sred)[32]) {
    int lid = threadIdx.x & 63;
    int wid = threadIdx.x >> 6;
    #pragma unroll
    for (int d = 0; d < 16; ++d) {
        float v = acc[d];
        float v2 = v * v;
        #pragma unroll
        for (int off = 32; off; off >>= 1) {
            v += __shfl_xor(v, off);
            v2 += __shfl_xor(v2, off);
        }
        if (lid == 0) { sred[wid][d] = v; sred[wid][16 + d] = v2; }
    }
    __syncthreads();
    if (threadIdx.x < 32)
        partials[(size_t)blockIdx.x * 32 + threadIdx.x] =
            sred[0][threadIdx.x] + sred[1][threadIdx.x] +
            sred[2][threadIdx.x] + sred[3][threadIdx.x];
}

// ---- redundant per-block reduce of partials -> scale/shift into LDS scsh[32] ----
__device__ __forceinline__ void reduce_scsh(const float* __restrict__ partials, int nbp,
                                            const float* __restrict__ gamma,
                                            const float* __restrict__ beta,
                                            float invN, float (*red)[33],
                                            float* __restrict__ scsh) {
    int ch = threadIdx.x & 31;
    int rg = threadIdx.x >> 5;    // 0..7
    float s0 = 0.f, s1 = 0.f, s2 = 0.f, s3 = 0.f;
    int j = rg;
    for (; j + 24 < nbp; j += 32) {
        s0 += partials[(size_t)(j     ) * 32 + ch];
        s1 += partials[(size_t)(j +  8) * 32 + ch];
        s2 += partials[(size_t)(j + 16) * 32 + ch];
        s3 += partials[(size_t)(j + 24) * 32 + ch];
    }
    for (; j < nbp; j += 8) s0 += partials[(size_t)j * 32 + ch];
    red[rg][ch] = (s0 + s1) + (s2 + s3);
    __syncthreads();
    if (threadIdx.x < 32) {
        float t = 0.f;
        #pragma unroll
        for (int r = 0; r < 8; ++r) t += red[r][threadIdx.x];
        red[0][threadIdx.x] = t;
    }
    __syncthreads();
    if (threadIdx.x < 16) {
        int d = threadIdx.x;
        float mean = red[0][d] * invN;
        float var  = red[0][16 + d] * invN - mean * mean;
        float sc = gamma[d] * rsqrtf(var + BN_EPS);
        scsh[d] = sc;
        scsh[16 + d] = beta[d] - mean * sc;
    }
    __syncthreads();
}

// ------ fused: build pairs (regs) + conv1 (C=3->16) + BN1 stats ------
__global__ void k_build_conv1(const int* __restrict__ coords, const int* __restrict__ bcnt,
                              const uint32_t* __restrict__ bent, const float* __restrict__ feat,
                              const float* __restrict__ w1,
                              int* __restrict__ pcnt, uint32_t* __restrict__ pairs,
                              float* __restrict__ h1, float* __restrict__ partials, int N) {
    __shared__ float ws[27 * 48];
    __shared__ float sred[4][32];
    for (int i = threadIdx.x; i < 27 * 48; i += blockDim.x) ws[i] = w1[i];
    __syncthreads();
    int n = blockIdx.x * blockDim.x + threadIdx.x;
    float acc[16];
    #pragma unroll
    for (int d = 0; d < 16; ++d) acc[d] = 0.f;
    if (n < N) {
        int4 c4 = ((const int4*)coords)[n];
        int z = c4.y, y = c4.z, x = c4.w;
        uint32_t lpairs[PCAP];
        int cnt = 0;
        int yb0 = (y - 1) >> 1;
        #pragma unroll
        for (int dz = -1; dz <= 1; ++dz) {
            int zz = z + dz;
            if ((unsigned)zz >= SPARSE_D) continue;
            #pragma unroll
            for (int t = 0; t < 2; ++t) {
                int yb = yb0 + t;
                if ((unsigned)yb >= NYB) continue;
                int b = zz * NYB + yb;
                int m = min(bcnt[b], BCAP);
                const uint4* p4 = (const uint4*)&bent[b * BCAP];
                for (int i = 0; i < m; i += 4) {
                    uint4 e4 = p4[i >> 2];
                    uint32_t es[4] = {e4.x, e4.y, e4.z, e4.w};
                    #pragma unroll
                    for (int j = 0; j < 4; ++j) {
                        if (i + j >= m) break;
                        uint32_t e = es[j];
                        int ey = (yb << 1) + (int)(e >> 29);
                        int ex = (int)((e >> 18) & 0x7FFu);
                        int dy = ey - y, dx = ex - x;
                        if ((unsigned)(dy + 1) > 2u || (unsigned)(dx + 1) > 2u) continue;
                        uint32_t idx = e & 0x3FFFFu;
                        if (idx == (uint32_t)n) continue;
                        int k = (dz + 1) * 9 + (dy + 1) * 3 + (dx + 1);
                        if (cnt < PCAP)
                            lpairs[cnt] = ((uint32_t)k << 18) | idx;
                        ++cnt;
                    }
                }
            }
        }
        cnt = min(cnt, PCAP);
        pcnt[n] = cnt;
        float f0 = feat[n * 3 + 0], f1 = feat[n * 3 + 1], f2 = feat[n * 3 + 2];
        const float* w = &ws[13 * 48];
        #pragma unroll
        for (int d = 0; d < 16; ++d)
            acc[d] = fmaf(f0, w[d], fmaf(f1, w[16 + d], f2 * w[32 + d]));
        for (int c = 0; c < cnt; ++c) {
            uint32_t pr = lpairs[c];
            pairs[(size_t)c * N + n] = pr;
            int k = (int)(pr >> 18), idx = (int)(pr & 0x3FFFFu);
            float g0 = feat[idx * 3 + 0], g1 = feat[idx * 3 + 1], g2 = feat[idx * 3 + 2];
            const float* wk = &ws[k * 48];
            #pragma unroll
            for (int d = 0; d < 16; ++d)
                acc[d] = fmaf(g0, wk[d], fmaf(g1, wk[16 + d], fmaf(g2, wk[32 + d], acc[d])));
        }
        float4* o = (float4*)&h1[(size_t)n * 16];
        o[0] = make_float4(acc[0], acc[1], acc[2], acc[3]);
        o[1] = make_float4(acc[4], acc[5], acc[6], acc[7]);
        o[2] = make_float4(acc[8], acc[9], acc[10], acc[11]);
        o[3] = make_float4(acc[12], acc[13], acc[14], acc[15]);
    }
    stats_epilogue(acc, partials, sred);
}

// ------- conv2: redundant BN1 finalize + fused BN1+ReLU loads + BN2 stats -------
__global__ void k_conv2(const float* __restrict__ h1, const int* __restrict__ pcnt,
                        const uint32_t* __restrict__ pairs, const float* __restrict__ w2,
                        const float* __restrict__ partials1, int nbp,
                        const float* __restrict__ gamma1, const float* __restrict__ beta1,
                        float invN, float* __restrict__ out,
                        float* __restrict__ partials2, int N) {
    __shared__ float ws[27 * 256];
    __shared__ float red[8][33];
    __shared__ float sred[4][32];
    __shared__ float scsh[32];
    for (int i = threadIdx.x; i < 27 * 256; i += blockDim.x) ws[i] = w2[i];
    reduce_scsh(partials1, nbp, gamma1, beta1, invN, red, scsh);
    int n = blockIdx.x * blockDim.x + threadIdx.x;
    float acc[16];
    #pragma unroll
    for (int d = 0; d < 16; ++d) acc[d] = 0.f;
    if (n < N) {
        float g[16];
        #pragma unroll
        for (int c = 0; c < 16; c += 4) {
            float4 t = *(const float4*)&h1[(size_t)n * 16 + c];
            g[c]     = fmaxf(fmaf(t.x, scsh[c],     scsh[16 + c]),     0.f);
            g[c + 1] = fmaxf(fmaf(t.y, scsh[c + 1], scsh[16 + c + 1]), 0.f);
            g[c + 2] = fmaxf(fmaf(t.z, scsh[c + 2], scsh[16 + c + 2]), 0.f);
            g[c + 3] = fmaxf(fmaf(t.w, scsh[c + 3], scsh[16 + c + 3]), 0.f);
        }
        {
            const float* w = &ws[13 * 256];
            #pragma unroll
            for (int c = 0; c < 16; ++c)
                #pragma unroll
                for (int d = 0; d < 16; ++d)
                    acc[d] = fmaf(g[c], w[c * 16 + d], acc[d]);
        }
        int m = min(pcnt[n], PCAP);
        for (int cc = 0; cc < m; ++cc) {
            uint32_t pr = pairs[(size_t)cc * N + n];
            int k = (int)(pr >> 18), idx = (int)(pr & 0x3FFFFu);
            #pragma unroll
            for (int c = 0; c < 16; c += 4) {
                float4 t = *(const float4*)&h1[(size_t)idx * 16 + c];
                g[c]     = fmaxf(fmaf(t.x, scsh[c],     scsh[16 + c]),     0.f);
                g[c + 1] = fmaxf(fmaf(t.y, scsh[c + 1], scsh[16 + c + 1]), 0.f);
                g[c + 2] = fmaxf(fmaf(t.z, scsh[c + 2], scsh[16 + c + 2]), 0.f);
                g[c + 3] = fmaxf(fmaf(t.w, scsh[c + 3], scsh[16 + c + 3]), 0.f);
            }
            const float* wk = &ws[k * 256];
            #pragma unroll
            for (int c = 0; c < 16; ++c)
                #pragma unroll
                for (int d = 0; d < 16; ++d)
                    acc[d] = fmaf(g[c], wk[c * 16 + d], acc[d]);
        }
        float4* o = (float4*)&out[(size_t)n * 16];
        o[0] = make_float4(acc[0], acc[1], acc[2], acc[3]);
        o[1] = make_float4(acc[4], acc[5], acc[6], acc[7]);
        o[2] = make_float4(acc[8], acc[9], acc[10], acc[11]);
        o[3] = make_float4(acc[12], acc[13], acc[14], acc[15]);
    }
    stats_epilogue(acc, partials2, sred);
}

// ------- bnrelu: redundant BN2 finalize + normalize out in place -------
__global__ void k_bnrelu(float* __restrict__ out, const float* __restrict__ partials2,
                         int nbp, const float* __restrict__ gamma2,
                         const float* __restrict__ beta2, float invN, int nvec) {
    __shared__ float red[8][33];
    __shared__ float scsh[32];
    reduce_scsh(partials2, nbp, gamma2, beta2, invN, red, scsh);
    int stride = gridDim.x * blockDim.x;
    for (int i = blockIdx.x * blockDim.x + threadIdx.x; i < nvec; i += stride) {
        float4 v = ((float4*)out)[i];
        int c0 = (i & 3) * 4;
        v.x = fmaxf(fmaf(v.x, scsh[c0 + 0], scsh[16 + c0 + 0]), 0.f);
        v.y = fmaxf(fmaf(v.y, scsh[c0 + 1], scsh[16 + c0 + 1]), 0.f);
        v.z = fmaxf(fmaf(v.z, scsh[c0 + 2], scsh[16 + c0 + 2]), 0.f);
        v.w = fmaxf(fmaf(v.w, scsh[c0 + 3], scsh[16 + c0 + 3]), 0.f);
        ((float4*)out)[i] = v;
    }
}

extern "C" void kernel_launch(void* const* d_in, const int* in_sizes, int n_in,
                              void* d_out, int out_size, void* d_ws, size_t ws_size,
                              hipStream_t stream) {
    const float* feat   = (const float*)d_in[0];
    const int*   coords = (const int*)d_in[1];
    const float* w1     = (const float*)d_in[2];
    const float* gamma1 = (const float*)d_in[3];
    const float* beta1  = (const float*)d_in[4];
    const float* w2     = (const float*)d_in[5];
    const float* gamma2 = (const float*)d_in[6];
    const float* beta2  = (const float*)d_in[7];
    float* out = (float*)d_out;
    const int N = in_sizes[0] / 3;

    const int T = 256;
    const int nb = (N + T - 1) / T;          // 782 blocks
    const int nvec = N * 16 / 4;
    const float invN = 1.f / (float)N;

    // workspace layout (64B aligned)
    char* ws = (char*)d_ws;
    size_t off = 0;
    int* bcnt = (int*)(ws + off);            off += ((size_t)NBUCKET * 4 + 63) & ~(size_t)63;
    uint32_t* bent = (uint32_t*)(ws + off);  off += (size_t)NBUCKET * BCAP * 4;      // 4.2 MB
    int* pcnt = (int*)(ws + off);            off += ((size_t)N * 4 + 63) & ~(size_t)63;
    uint32_t* pairs = (uint32_t*)(ws + off); off += (size_t)PCAP * N * 4;            // 9.6 MB
    float* h1 = (float*)(ws + off);          off += (size_t)N * 16 * 4;              // 12.8 MB
    float* partials1 = (float*)(ws + off);   off += ((size_t)nb * 32 * 4 + 63) & ~(size_t)63;
    float* partials2 = (float*)(ws + off);   off += ((size_t)nb * 32 * 4 + 63) & ~(size_t)63;

    hipMemsetAsync(bcnt, 0, (size_t)NBUCKET * 4, stream);
    k_insert<<<nb, T, 0, stream>>>(coords, bcnt, bent, N);
    k_build_conv1<<<nb, T, 0, stream>>>(coords, bcnt, bent, feat, w1, pcnt, pairs, h1, partials1, N);
    k_conv2<<<nb, T, 0, stream>>>(h1, pcnt, pairs, w2, partials1, nb, gamma1, beta1, invN,
                                  out, partials2, N);
    k_bnrelu<<<nb, T, 0, stream>>>(out, partials2, nb, gamma2, beta2, invN, nvec);
}

// Round 8
// 154.509 us; speedup vs baseline: 3.3069x; 1.0758x over previous
//
#include <hip/hip_runtime.h>
#include <stdint.h>

#define SPARSE_D 41
#define SPARSE_H 1600
#define SPARSE_W 1408
#define BN_EPS 0.001f

static constexpr int NYB = SPARSE_H / 2;          // 800
static constexpr int NBUCKET = SPARSE_D * NYB;    // 32,800
static constexpr int PCAP = 12;                   // max non-self pairs per voxel (lambda~0.056)

// bucket = z*NYB + (y>>1): 32 uint32 words (128B). word0 = count, words 1..31 = entries.
// Avg count 6.1 (Poisson): line0 (count + 15 entries) covers P~0.9985 of buckets.
// entry: [29]=y&1, [28:18]=x (11b), [17:0]=idx ; pair: [22:18]=k, [17:0]=idx

// ---------------- scatter voxels into buckets (count in word0) ----------------
__global__ void k_insert(const int* __restrict__ coords, uint32_t* __restrict__ bent, int N) {
    int n = blockIdx.x * blockDim.x + threadIdx.x;
    if (n >= N) return;
    int4 c4 = ((const int4*)coords)[n];
    int z = c4.y, y = c4.z, x = c4.w;
    int b = z * NYB + (y >> 1);
    uint32_t e = ((uint32_t)(y & 1) << 29) | ((uint32_t)x << 18) | (uint32_t)n;
    int slot = atomicAdd((int*)&bent[(size_t)b * 32], 1) + 1;
    if (slot <= 31) bent[(size_t)b * 32 + slot] = e;
}

// ---- stats epilogue: wave shuffle reduce -> LDS -> per-block partials ----
__device__ __forceinline__ void stats_epilogue(const float acc[16],
                                               float* __restrict__ partials,
                                               float (*sred)[32]) {
    int lid = threadIdx.x & 63;
    int wid = threadIdx.x >> 6;
    #pragma unroll
    for (int d = 0; d < 16; ++d) {
        float v = acc[d];
        float v2 = v * v;
        #pragma unroll
        for (int off = 32; off; off >>= 1) {
            v += __shfl_xor(v, off);
            v2 += __shfl_xor(v2, off);
        }
        if (lid == 0) { sred[wid][d] = v; sred[wid][16 + d] = v2; }
    }
    __syncthreads();
    if (threadIdx.x < 32)
        partials[(size_t)blockIdx.x * 32 + threadIdx.x] =
            sred[0][threadIdx.x] + sred[1][threadIdx.x] +
            sred[2][threadIdx.x] + sred[3][threadIdx.x];
}

// ------ fused: build pairs (regs) + conv1 (C=3->16, weights from global) + BN1 stats ------
__global__ void k_build_conv1(const int* __restrict__ coords, const uint32_t* __restrict__ bent,
                              const float* __restrict__ feat, const float* __restrict__ w1,
                              int* __restrict__ pcnt, uint32_t* __restrict__ pairs,
                              float* __restrict__ h1, float* __restrict__ partials, int N) {
    __shared__ float sred[4][32];
    int n = blockIdx.x * blockDim.x + threadIdx.x;
    float acc[16];
    #pragma unroll
    for (int d = 0; d < 16; ++d) acc[d] = 0.f;
    if (n < N) {
        int4 c4 = ((const int4*)coords)[n];
        int z = c4.y, y = c4.z, x = c4.w;

        // self term first (uniform weight pointer -> scalar loads; overlaps with probes)
        float f0 = feat[n * 3 + 0], f1 = feat[n * 3 + 1], f2 = feat[n * 3 + 2];
        const float* wd = w1 + 13 * 48;
        #pragma unroll
        for (int d = 0; d < 16; ++d)
            acc[d] = fmaf(f0, wd[d], fmaf(f1, wd[16 + d], f2 * wd[32 + d]));

        // preload all 6 bucket line0s unconditionally (masked -> bucket 0) for MLP
        int yb0 = (y - 1) >> 1;
        uint4 q0[6];
        int bix[6], mm[6];
        #pragma unroll
        for (int p = 0; p < 6; ++p) {
            int zz = z + p / 2 - 1;
            int yb = yb0 + (p & 1);
            bool v = ((unsigned)zz < SPARSE_D) & ((unsigned)yb < NYB);
            int b = v ? (zz * NYB + yb) : 0;
            bix[p] = b;
            q0[p] = *(const uint4*)&bent[(size_t)b * 32];
            mm[p] = v ? 1 : 0;   // patched below with count
        }

        uint32_t lpairs[PCAP];
        int cnt = 0;
        #pragma unroll
        for (int p = 0; p < 6; ++p) {
            int m = mm[p] ? min((int)q0[p].x, 31) : 0;
            int yb = yb0 + (p & 1);
            int dzk = (p / 2) * 9;
            auto scan_entry = [&](uint32_t e, int slot) {
                if (slot > m) return;
                int ey = (yb << 1) + (int)(e >> 29);
                int ex = (int)((e >> 18) & 0x7FFu);
                int dy = ey - y, dx = ex - x;
                if ((unsigned)(dy + 1) > 2u || (unsigned)(dx + 1) > 2u) return;
                uint32_t idx = e & 0x3FFFFu;
                if (idx == (uint32_t)n) return;
                int k = dzk + (dy + 1) * 3 + (dx + 1);
                if (cnt < PCAP) lpairs[cnt] = ((uint32_t)k << 18) | idx;
                ++cnt;
            };
            scan_entry(q0[p].y, 1);
            scan_entry(q0[p].z, 2);
            scan_entry(q0[p].w, 3);
            for (int w = 4; w <= m; w += 4) {
                uint4 q = *(const uint4*)&bent[(size_t)bix[p] * 32 + w];
                scan_entry(q.x, w);
                scan_entry(q.y, w + 1);
                scan_entry(q.z, w + 2);
                scan_entry(q.w, w + 3);
            }
        }
        cnt = min(cnt, PCAP);
        pcnt[n] = cnt;
        for (int c = 0; c < cnt; ++c) {
            uint32_t pr = lpairs[c];
            pairs[(size_t)c * N + n] = pr;
            int k = (int)(pr >> 18), idx = (int)(pr & 0x3FFFFu);
            float g0 = feat[idx * 3 + 0], g1 = feat[idx * 3 + 1], g2 = feat[idx * 3 + 2];
            const float* wk = w1 + k * 48;     // L1-resident (5.2 KB total)
            #pragma unroll
            for (int d = 0; d < 16; ++d)
                acc[d] = fmaf(g0, wk[d], fmaf(g1, wk[16 + d], fmaf(g2, wk[32 + d], acc[d])));
        }
        float4* o = (float4*)&h1[(size_t)n * 16];
        o[0] = make_float4(acc[0], acc[1], acc[2], acc[3]);
        o[1] = make_float4(acc[4], acc[5], acc[6], acc[7]);
        o[2] = make_float4(acc[8], acc[9], acc[10], acc[11]);
        o[3] = make_float4(acc[12], acc[13], acc[14], acc[15]);
    }
    stats_epilogue(acc, partials, sred);
}

// ------- conv2: C=16->16, weights from global/L1, BN1+ReLU fused on load -------
__global__ void k_conv2(const float* __restrict__ h1, const int* __restrict__ pcnt,
                        const uint32_t* __restrict__ pairs, const float* __restrict__ w2,
                        const float* __restrict__ scsh1, float* __restrict__ out,
                        float* __restrict__ partials, int N) {
    __shared__ float sred[4][32];
    __shared__ float sc[16], sh[16];
    if (threadIdx.x < 16) { sc[threadIdx.x] = scsh1[threadIdx.x]; sh[threadIdx.x] = scsh1[16 + threadIdx.x]; }
    __syncthreads();
    int n = blockIdx.x * blockDim.x + threadIdx.x;
    float acc[16];
    #pragma unroll
    for (int d = 0; d < 16; ++d) acc[d] = 0.f;
    if (n < N) {
        float g[16];
        #pragma unroll
        for (int c = 0; c < 16; c += 4) {
            float4 t = *(const float4*)&h1[(size_t)n * 16 + c];
            g[c]     = fmaxf(fmaf(t.x, sc[c],     sh[c]),     0.f);
            g[c + 1] = fmaxf(fmaf(t.y, sc[c + 1], sh[c + 1]), 0.f);
            g[c + 2] = fmaxf(fmaf(t.z, sc[c + 2], sh[c + 2]), 0.f);
            g[c + 3] = fmaxf(fmaf(t.w, sc[c + 3], sh[c + 3]), 0.f);
        }
        {
            const float* w = w2 + 13 * 256;    // uniform -> scalar-cache loads
            #pragma unroll
            for (int c = 0; c < 16; ++c)
                #pragma unroll
                for (int d = 0; d < 16; ++d)
                    acc[d] = fmaf(g[c], w[c * 16 + d], acc[d]);
        }
        int m = min(pcnt[n], PCAP);
        for (int cc = 0; cc < m; ++cc) {
            uint32_t pr = pairs[(size_t)cc * N + n];
            int k = (int)(pr >> 18), idx = (int)(pr & 0x3FFFFu);
            #pragma unroll
            for (int c = 0; c < 16; c += 4) {
                float4 t = *(const float4*)&h1[(size_t)idx * 16 + c];
                g[c]     = fmaxf(fmaf(t.x, sc[c],     sh[c]),     0.f);
                g[c + 1] = fmaxf(fmaf(t.y, sc[c + 1], sh[c + 1]), 0.f);
                g[c + 2] = fmaxf(fmaf(t.z, sc[c + 2], sh[c + 2]), 0.f);
                g[c + 3] = fmaxf(fmaf(t.w, sc[c + 3], sh[c + 3]), 0.f);
            }
            const float* wk = w2 + k * 256;    // L1-resident (27.6 KB total)
            #pragma unroll
            for (int c = 0; c < 16; ++c)
                #pragma unroll
                for (int d = 0; d < 16; ++d)
                    acc[d] = fmaf(g[c], wk[c * 16 + d], acc[d]);
        }
        float4* o = (float4*)&out[(size_t)n * 16];
        o[0] = make_float4(acc[0], acc[1], acc[2], acc[3]);
        o[1] = make_float4(acc[4], acc[5], acc[6], acc[7]);
        o[2] = make_float4(acc[8], acc[9], acc[10], acc[11]);
        o[3] = make_float4(acc[12], acc[13], acc[14], acc[15]);
    }
    stats_epilogue(acc, partials, sred);
}

// ------- finalize: 1024 threads, 32 row-groups x 32 channels, 4-way ILP -------
__global__ void k_finalize(const float* __restrict__ partials, int nb,
                           const float* __restrict__ gamma, const float* __restrict__ beta,
                           float* __restrict__ scsh, float invN) {
    __shared__ float red[32][33];
    int ch = threadIdx.x & 31;
    int rg = threadIdx.x >> 5;   // 0..31
    float s0 = 0.f, s1 = 0.f, s2 = 0.f, s3 = 0.f;
    int j = rg;
    for (; j + 96 < nb; j += 128) {
        s0 += partials[(size_t)(j      ) * 32 + ch];
        s1 += partials[(size_t)(j + 32 ) * 32 + ch];
        s2 += partials[(size_t)(j + 64 ) * 32 + ch];
        s3 += partials[(size_t)(j + 96 ) * 32 + ch];
    }
    for (; j < nb; j += 32) s0 += partials[(size_t)j * 32 + ch];
    red[rg][ch] = (s0 + s1) + (s2 + s3);
    __syncthreads();
    if (threadIdx.x < 32) {
        float t = 0.f;
        #pragma unroll
        for (int r = 0; r < 32; ++r) t += red[r][threadIdx.x];
        red[0][threadIdx.x] = t;
    }
    __syncthreads();
    if (threadIdx.x < 16) {
        int d = threadIdx.x;
        float mean = red[0][d] * invN;
        float var = red[0][16 + d] * invN - mean * mean;
        float s2c = gamma[d] * rsqrtf(var + BN_EPS);
        scsh[d] = s2c;
        scsh[16 + d] = beta[d] - mean * s2c;
    }
}

// ---------------- elementwise BN+ReLU (float4 per thread) ----------------
__global__ void k_bnrelu4(float* __restrict__ x, const float* __restrict__ scsh, int nvec) {
    __shared__ float sc[16], sh[16];
    if (threadIdx.x < 16) { sc[threadIdx.x] = scsh[threadIdx.x]; sh[threadIdx.x] = scsh[16 + threadIdx.x]; }
    __syncthreads();
    int i = blockIdx.x * blockDim.x + threadIdx.x;
    if (i < nvec) {
        float4 v = ((float4*)x)[i];
        int c0 = (i & 3) * 4;
        v.x = fmaxf(fmaf(v.x, sc[c0 + 0], sh[c0 + 0]), 0.f);
        v.y = fmaxf(fmaf(v.y, sc[c0 + 1], sh[c0 + 1]), 0.f);
        v.z = fmaxf(fmaf(v.z, sc[c0 + 2], sh[c0 + 2]), 0.f);
        v.w = fmaxf(fmaf(v.w, sc[c0 + 3], sh[c0 + 3]), 0.f);
        ((float4*)x)[i] = v;
    }
}

extern "C" void kernel_launch(void* const* d_in, const int* in_sizes, int n_in,
                              void* d_out, int out_size, void* d_ws, size_t ws_size,
                              hipStream_t stream) {
    const float* feat   = (const float*)d_in[0];
    const int*   coords = (const int*)d_in[1];
    const float* w1     = (const float*)d_in[2];
    const float* gamma1 = (const float*)d_in[3];
    const float* beta1  = (const float*)d_in[4];
    const float* w2     = (const float*)d_in[5];
    const float* gamma2 = (const float*)d_in[6];
    const float* beta2  = (const float*)d_in[7];
    float* out = (float*)d_out;
    const int N = in_sizes[0] / 3;

    const int T = 256;
    const int nb = (N + T - 1) / T;          // 782 blocks
    const int nvec = N * 16 / 4;
    const int nbv = (nvec + T - 1) / T;

    // workspace layout (64B aligned)
    char* ws = (char*)d_ws;
    size_t off = 0;
    uint32_t* bent = (uint32_t*)(ws + off);  off += (size_t)NBUCKET * 32 * 4;        // 4.2 MB
    int* pcnt = (int*)(ws + off);            off += ((size_t)N * 4 + 63) & ~(size_t)63;
    uint32_t* pairs = (uint32_t*)(ws + off); off += (size_t)PCAP * N * 4;            // 9.6 MB
    float* h1 = (float*)(ws + off);          off += (size_t)N * 16 * 4;              // 12.8 MB
    float* partials = (float*)(ws + off);    off += ((size_t)nb * 32 * 4 + 63) & ~(size_t)63;
    float* stats = (float*)(ws + off);       // [0:32] sc/sh 1, [32:64] sc/sh 2

    hipMemsetAsync(bent, 0, (size_t)NBUCKET * 32 * 4, stream);
    k_insert<<<nb, T, 0, stream>>>(coords, bent, N);
    k_build_conv1<<<nb, T, 0, stream>>>(coords, bent, feat, w1, pcnt, pairs, h1, partials, N);
    k_finalize<<<1, 1024, 0, stream>>>(partials, nb, gamma1, beta1, stats, 1.f / (float)N);
    k_conv2<<<nb, T, 0, stream>>>(h1, pcnt, pairs, w2, stats, out, partials, N);
    k_finalize<<<1, 1024, 0, stream>>>(partials, nb, gamma2, beta2, stats + 32, 1.f / (float)N);
    k_bnrelu4<<<nbv, T, 0, stream>>>(out, stats + 32, nvec);
}